// Round 4
// baseline (236.404 us; speedup 1.0000x reference)
//
#include <hip/hip_runtime.h>
#include <hip/hip_bf16.h>

#define HID 16
#define RANGE_BITS 9
#define RANGE (1 << RANGE_BITS)          // 512 nodes per range
#define SRC_BITS 17                      // N=100000 < 2^17
#define SRC_MASK ((1u << SRC_BITS) - 1)
#define NR_MAX 256
#define GCUR_STRIDE 16                   // one 64B line per range cursor
#define PART_BLOCK 256
#define PART_K 16
#define TILE (PART_BLOCK * PART_K)       // 4096 edges per tile
#define SCAT_BLOCK 256

// ---------------- init: zero the (padded) range cursors ----------------
__global__ void k_init(int* __restrict__ gcur) {
    int i = blockIdx.x * blockDim.x + threadIdx.x;
    if (i < NR_MAX * GCUR_STRIDE) gcur[i] = 0;
}

// ---------------- partition edges by dst range, packed (dloc<<17)|src --------
__global__ void k_partition(const int* __restrict__ src, const int* __restrict__ dst,
                            unsigned* __restrict__ buckets, int* __restrict__ gcur,
                            int E, int nr, int cap) {
    __shared__ int cnt[NR_MAX];
    __shared__ int base[NR_MAX];
    int tb = blockIdx.x * TILE;
    if (threadIdx.x < nr) cnt[threadIdx.x] = 0;
    __syncthreads();
    int rr[PART_K]; int rk[PART_K]; unsigned pk[PART_K];
#pragma unroll
    for (int k = 0; k < PART_K; k++) {
        int e = tb + k * PART_BLOCK + threadIdx.x;
        if (e < E) {
            int d = dst[e];
            int s = src[e];
            int r = d >> RANGE_BITS;
            rr[k] = r;
            pk[k] = ((unsigned)(d & (RANGE - 1)) << SRC_BITS) | (unsigned)s;
            rk[k] = atomicAdd(&cnt[r], 1);
        } else {
            rr[k] = -1; rk[k] = 0; pk[k] = 0;
        }
    }
    __syncthreads();
    if (threadIdx.x < nr && cnt[threadIdx.x] > 0)
        base[threadIdx.x] = atomicAdd(&gcur[threadIdx.x * GCUR_STRIDE], cnt[threadIdx.x]);
    __syncthreads();
#pragma unroll
    for (int k = 0; k < PART_K; k++) {
        if (rr[k] >= 0) {
            int idx = base[rr[k]] + rk[k];
            if (idx < cap)   // capacity guard (~7.6 sigma slack)
                buckets[(size_t)rr[k] * cap + idx] = pk[k];
        }
    }
}

// ---------------- scalar binned scatter: 2KB LDS bins -> private partials ----
__global__ void __launch_bounds__(SCAT_BLOCK)
k_scatter_f1(const unsigned* __restrict__ buckets, const int* __restrict__ gcur,
             const float* __restrict__ val, float* __restrict__ partial,
             int nc, int cap) {
    __shared__ float bins[RANGE];
    int r = blockIdx.x / nc, c = blockIdx.x % nc;
    int cnt = gcur[r * GCUR_STRIDE];
    int seg = (((cnt + nc - 1) / nc) + 3) & ~3;
    int b0 = c * seg;
    int b1 = min(cnt, b0 + seg);
    for (int i = threadIdx.x; i < RANGE; i += SCAT_BLOCK) bins[i] = 0.f;
    __syncthreads();
    const unsigned* bk = buckets + (size_t)r * cap;
    int e = b0 + (threadIdx.x << 2);
    for (; e + 4 <= b1; e += (SCAT_BLOCK << 2)) {
        uint4 p = *(const uint4*)(bk + e);
        float v0 = val[p.x & SRC_MASK];
        float v1 = val[p.y & SRC_MASK];
        float v2 = val[p.z & SRC_MASK];
        float v3 = val[p.w & SRC_MASK];
        atomicAdd(&bins[p.x >> SRC_BITS], v0);
        atomicAdd(&bins[p.y >> SRC_BITS], v1);
        atomicAdd(&bins[p.z >> SRC_BITS], v2);
        atomicAdd(&bins[p.w >> SRC_BITS], v3);
    }
    int e1 = min(b1, e + 4);
    for (int q = e; q < e1; q++) {
        unsigned pk = bk[q];
        atomicAdd(&bins[pk >> SRC_BITS], val[pk & SRC_MASK]);
    }
    __syncthreads();
    float* p = partial + (size_t)blockIdx.x * RANGE;
    for (int i = threadIdx.x; i < RANGE; i += SCAT_BLOCK) p[i] = bins[i];
}

// ---------------- float2 binned scatter, 8 edges/thread, separate planes -----
__global__ void __launch_bounds__(SCAT_BLOCK)
k_scatter_f2(const unsigned* __restrict__ buckets, const int* __restrict__ gcur,
             const float* __restrict__ val2, float* __restrict__ partial,
             int nc, int cap) {
    __shared__ float ba[RANGE];
    __shared__ float bb[RANGE];
    int r = blockIdx.x / nc, c = blockIdx.x % nc;
    int cnt = gcur[r * GCUR_STRIDE];
    int seg = (((cnt + nc - 1) / nc) + 7) & ~7;
    int b0 = c * seg;
    int b1 = min(cnt, b0 + seg);
    for (int i = threadIdx.x; i < RANGE; i += SCAT_BLOCK) { ba[i] = 0.f; bb[i] = 0.f; }
    __syncthreads();
    const unsigned* bk = buckets + (size_t)r * cap;
    const float2* v2 = (const float2*)val2;
    int e = b0 + (threadIdx.x << 3);
    for (; e + 8 <= b1; e += (SCAT_BLOCK << 3)) {
        uint4 p0 = *(const uint4*)(bk + e);
        uint4 p1 = *(const uint4*)(bk + e + 4);
        float2 v0 = v2[p0.x & SRC_MASK];
        float2 v1 = v2[p0.y & SRC_MASK];
        float2 w2 = v2[p0.z & SRC_MASK];
        float2 w3 = v2[p0.w & SRC_MASK];
        float2 v4 = v2[p1.x & SRC_MASK];
        float2 v5 = v2[p1.y & SRC_MASK];
        float2 v6 = v2[p1.z & SRC_MASK];
        float2 v7 = v2[p1.w & SRC_MASK];
        atomicAdd(&ba[p0.x >> SRC_BITS], v0.x); atomicAdd(&bb[p0.x >> SRC_BITS], v0.y);
        atomicAdd(&ba[p0.y >> SRC_BITS], v1.x); atomicAdd(&bb[p0.y >> SRC_BITS], v1.y);
        atomicAdd(&ba[p0.z >> SRC_BITS], w2.x); atomicAdd(&bb[p0.z >> SRC_BITS], w2.y);
        atomicAdd(&ba[p0.w >> SRC_BITS], w3.x); atomicAdd(&bb[p0.w >> SRC_BITS], w3.y);
        atomicAdd(&ba[p1.x >> SRC_BITS], v4.x); atomicAdd(&bb[p1.x >> SRC_BITS], v4.y);
        atomicAdd(&ba[p1.y >> SRC_BITS], v5.x); atomicAdd(&bb[p1.y >> SRC_BITS], v5.y);
        atomicAdd(&ba[p1.z >> SRC_BITS], v6.x); atomicAdd(&bb[p1.z >> SRC_BITS], v6.y);
        atomicAdd(&ba[p1.w >> SRC_BITS], v7.x); atomicAdd(&bb[p1.w >> SRC_BITS], v7.y);
    }
    int e1 = min(b1, e + 8);
    for (int q = e; q < e1; q++) {
        unsigned pk = bk[q];
        float2 v = v2[pk & SRC_MASK];
        atomicAdd(&ba[pk >> SRC_BITS], v.x);
        atomicAdd(&bb[pk >> SRC_BITS], v.y);
    }
    __syncthreads();
    float* pa = partial + (size_t)blockIdx.x * 2 * RANGE;
    for (int i = threadIdx.x; i < RANGE; i += SCAT_BLOCK) {
        pa[i] = ba[i];
        pa[RANGE + i] = bb[i];
    }
}

// ---------------- fused reduce(D1) + encode ---------------------------------
// u1 = Wp_rel·wd_rel, u2 = Wp_rel·wd_root, v1 = Wp_root·wd_rel, v2 = Wp_root·wd_root
__global__ void k_encode(const float* __restrict__ x, const float* __restrict__ partial,
                         int nc,
                         const float* __restrict__ ewrel, const float* __restrict__ ewroot,
                         const float* __restrict__ eb,
                         const float* __restrict__ pwrel, const float* __restrict__ pwroot,
                         const float* __restrict__ dwrel, const float* __restrict__ dwroot,
                         float* __restrict__ SAB, float* __restrict__ G1,
                         float* __restrict__ G2, int N) {
    __shared__ float su1[HID], su2[HID], sv1[HID], sv2[HID];
    __shared__ float swr[HID], swo[HID], sbb[HID];
    int t = threadIdx.x;
    if (t < 64) {
        int k = t & 15, w = t >> 4;
        const float* M  = (w < 2) ? pwrel : pwroot;
        const float* vv = ((w & 1) == 0) ? dwrel : dwroot;
        float acc = 0.f;
        for (int h = 0; h < HID; h++) acc += M[k * HID + h] * vv[h];
        if (w == 0) su1[k] = acc;
        else if (w == 1) su2[k] = acc;
        else if (w == 2) sv1[k] = acc;
        else sv2[k] = acc;
    }
    if (t < HID) { swr[t] = ewrel[t]; swo[t] = ewroot[t]; sbb[t] = eb[t]; }
    __syncthreads();
    int i = blockIdx.x * blockDim.x + t;
    if (i >= N) return;
    int r = i >> RANGE_BITS, dl = i & (RANGE - 1);
    float a1 = 0.f;
    for (int c = 0; c < nc; c++)
        a1 += partial[((size_t)(r * nc + c) << RANGE_BITS) + dl];
    float xi = x[i];
    float sa = 0.f, sb = 0.f, g1 = 0.f, g2 = 0.f;
#pragma unroll
    for (int h = 0; h < HID; h++) {
        float z = fmaxf(fmaf(a1, swr[h], fmaf(xi, swo[h], sbb[h])), 0.f);
        sa = fmaf(z, su1[h], sa);
        sb = fmaf(z, su2[h], sb);
        g1 = fmaf(z, sv1[h], g1);
        g2 = fmaf(z, sv2[h], g2);
    }
    SAB[2 * i] = sa; SAB[2 * i + 1] = sb; G1[i] = g1; G2[i] = g2;
}

// ---------------- fused reduce(D2) + mid ------------------------------------
__global__ void k_mid(const float* __restrict__ partial, int nc,
                      const float* __restrict__ G1, const float* __restrict__ G2,
                      const float* __restrict__ pb, const float* __restrict__ dwrel,
                      const float* __restrict__ dwroot, const float* __restrict__ db,
                      float* __restrict__ BETA, float* __restrict__ R, int N) {
    __shared__ float sc1, sc2, sbd;
    if (threadIdx.x == 0) {
        float c1 = 0.f, c2 = 0.f;
        for (int h = 0; h < HID; h++) { c1 += pb[h] * dwrel[h]; c2 += pb[h] * dwroot[h]; }
        sc1 = c1; sc2 = c2; sbd = db[0];
    }
    __syncthreads();
    int i = blockIdx.x * blockDim.x + threadIdx.x;
    if (i >= N) return;
    int r = i >> RANGE_BITS, dl = i & (RANGE - 1);
    float sa = 0.f, sb = 0.f;
    for (int c = 0; c < nc; c++) {
        const float* pa = partial + ((size_t)(r * nc + c) * 2 << RANGE_BITS);
        sa += pa[dl];
        sb += pa[RANGE + dl];
    }
    BETA[i] = sa + G1[i] + sc1;
    R[i]    = sb + G2[i] + sc2 + sbd;
}

// ---------------- fused reduce(D3) + final ----------------------------------
__global__ void k_final(const float* __restrict__ partial, int nc,
                        const float* __restrict__ R,
                        float* __restrict__ out, int N) {
    int i = blockIdx.x * blockDim.x + threadIdx.x;
    if (i >= N) return;
    int r = i >> RANGE_BITS, dl = i & (RANGE - 1);
    float s = 0.f;
    for (int c = 0; c < nc; c++)
        s += partial[((size_t)(r * nc + c) << RANGE_BITS) + dl];
    out[i] = fmaxf(s + R[i], 0.f);
}

// ---------------- launch ----------------
extern "C" void kernel_launch(void* const* d_in, const int* in_sizes, int n_in,
                              void* d_out, int out_size, void* d_ws, size_t ws_size,
                              hipStream_t stream) {
    const float* x      = (const float*)d_in[0];
    const int*   ei     = (const int*)d_in[1];
    const float* ewrel  = (const float*)d_in[2];
    const float* ewroot = (const float*)d_in[3];
    const float* eb     = (const float*)d_in[4];
    const float* pwrel  = (const float*)d_in[5];
    const float* pwroot = (const float*)d_in[6];
    const float* pb     = (const float*)d_in[7];
    const float* dwrel  = (const float*)d_in[8];
    const float* dwroot = (const float*)d_in[9];
    const float* db     = (const float*)d_in[10];
    float* out = (float*)d_out;

    const int N = in_sizes[0];
    const int E = in_sizes[1] / 2;
    const int* src = ei;
    const int* dst = ei + E;

    const int nr = (N + RANGE - 1) >> RANGE_BITS;     // 196
    int cap = E / nr + 1024;
    cap = (cap + 7) & ~7;                              // 32B-aligned rows

    // workspace layout (4-byte words)
    size_t words = ws_size / 4;
    size_t off = 0;
    int* gcur = (int*)d_ws;                    off += NR_MAX * GCUR_STRIDE;
    unsigned* buckets = (unsigned*)d_ws + off; off += (size_t)nr * cap;
    float* SAB  = (float*)d_ws + off;          off += (size_t)2 * N;
    float* G1   = (float*)d_ws + off;          off += N;
    float* G2   = (float*)d_ws + off;          off += N;
    float* BETA = (float*)d_ws + off;          off += N;
    float* R    = (float*)d_ws + off;          off += N;
    // shared partial buffer: f2 needs nc2*nr*2*RANGE words; f1 uses nc1=2*nc2
    // planes of nr*RANGE words (identical footprint). Size nc2 from what's left.
    size_t avail = (words > off) ? (words - off) : 0;
    int nc2 = (int)(avail / ((size_t)nr * 2 * RANGE));
    if (nc2 > 16) nc2 = 16;
    if (nc2 < 1) nc2 = 1;
    int nc1 = 2 * nc2;
    float* partial = (float*)d_ws + off;

    const int ntiles = (E + TILE - 1) / TILE;
    const int nodeBlocks = (N + 255) / 256;

    hipLaunchKernelGGL(k_init, dim3((NR_MAX * GCUR_STRIDE + 255) / 256), dim3(256), 0,
                       stream, gcur);
    hipLaunchKernelGGL(k_partition, dim3(ntiles), dim3(PART_BLOCK), 0, stream,
                       src, dst, buckets, gcur, E, nr, cap);

    // pass 1: scatter(x) -> partials; fused reduce in k_encode
    hipLaunchKernelGGL(k_scatter_f1, dim3(nr * nc1), dim3(SCAT_BLOCK), 0, stream,
                       buckets, gcur, x, partial, nc1, cap);
    hipLaunchKernelGGL(k_encode, dim3(nodeBlocks), dim3(256), 0, stream,
                       x, partial, nc1, ewrel, ewroot, eb, pwrel, pwroot,
                       dwrel, dwroot, SAB, G1, G2, N);

    // pass 2: scatter(float2(a,b)) -> partials; fused reduce in k_mid
    hipLaunchKernelGGL(k_scatter_f2, dim3(nr * nc2), dim3(SCAT_BLOCK), 0, stream,
                       buckets, gcur, SAB, partial, nc2, cap);
    hipLaunchKernelGGL(k_mid, dim3(nodeBlocks), dim3(256), 0, stream,
                       partial, nc2, G1, G2, pb, dwrel, dwroot, db, BETA, R, N);

    // pass 3: scatter(BETA) -> partials; fused reduce in k_final
    hipLaunchKernelGGL(k_scatter_f1, dim3(nr * nc1), dim3(SCAT_BLOCK), 0, stream,
                       buckets, gcur, BETA, partial, nc1, cap);
    hipLaunchKernelGGL(k_final, dim3(nodeBlocks), dim3(256), 0, stream,
                       partial, nc1, R, out, N);
}